// Round 1
// baseline (195.875 us; speedup 1.0000x reference)
//
#include <hip/hip_runtime.h>
#include <math.h>

// Closed-form replacement for the reference:
//   - spectrum has exactly 2 nonzero bins per (b,c) plane: (h0,w0) and (511-h0,511-w0),
//     both with value 1 + i*phase
//   - ifft2 real part: v[y,x] = cos(t1) - p*sin(t1) + cos(t2) - p*sin(t2), scaled 1/(H*W)
//     t1 = 2*pi*((h0*y + w0*x) mod 512)/512 ; t2 with (511-h0, 511-w0)
//   - Parseval gives the plane L2 norm analytically: sum(w^2) = S/(H*W),
//     S = s1 + s2, s_i = (1+p^2)/2 unless the bin is self-conjugate (then 1)
//   - out = clip(x + 16*strength/(512*sqrt(S)) * v, 0, 1)

namespace {

constexpr int H = 512, W = 512, B = 32, C = 3;
constexpr int ROWS = 32;   // rows of one plane handled per block
constexpr int TPB = 256;   // 128 thread-groups of float4 cover a 512-wide row; 2 rows/iter

__global__ __launch_bounds__(TPB) void fourier_noise_kernel(
    const float* __restrict__ xin,
    const float* __restrict__ phases,
    const float* __restrict__ strengths,
    const int* __restrict__ idx_h,
    const int* __restrict__ idx_w,
    float* __restrict__ out)
{
    const int pl = blockIdx.y;            // plane 0..95  (= b*C + c)
    const int b  = pl / C;
    const int c  = pl % C;

    // invert the CRT pairing: find i in [0,96) with i%32==b, i%3==c
    // i = b + 32k, 32 == 2 (mod 3)  =>  2k == c-b (mod 3)  =>  k == 2*(c-b) (mod 3)
    int d = (c - b) % 3; if (d < 0) d += 3;
    const int k = (2 * d) % 3;
    const int i = b + B * k;

    const int   h0 = idx_h[i];
    const int   w0 = idx_w[i];
    const float p  = phases[i];
    const float st = strengths[b * C + c];

    // analytic plane norm (Parseval)
    const float halfE = 0.5f * (1.0f + p * p);
    const float s1 = (((h0 & 255) == 0) && ((w0 & 255) == 0)) ? 1.0f : halfE;
    const float s2 = ((h0 == 255 || h0 == 511) && (w0 == 255 || w0 == 511)) ? 1.0f : halfE;
    const float S  = s1 + s2;
    // g = scale * strength / sqrt(H*W*S),  scale = 512/32 = 16, sqrt(H*W)=512
    const float g = (16.0f / 512.0f) * st * rsqrtf(S);

    const int h0r = 511 - h0;
    const int w0r = 511 - w0;
    constexpr float STEP = 6.28318530717958647692f / 512.0f;  // 2*pi/512

    // per-row folded coefficients: v = cx1*A1 + sx1*B1 + cx2*A2 + sx2*B2
    __shared__ float4 rowtab[ROWS];
    const int row0 = blockIdx.x * ROWS;
    for (int r = threadIdx.x; r < ROWS; r += TPB) {
        const int y = row0 + r;
        float sy1, cy1, sy2, cy2;
        sincosf(float((h0  * y) & 511) * STEP, &sy1, &cy1);
        sincosf(float((h0r * y) & 511) * STEP, &sy2, &cy2);
        rowtab[r] = make_float4(fmaf(-p, sy1, cy1), -fmaf(p, cy1, sy1),
                                fmaf(-p, sy2, cy2), -fmaf(p, cy2, sy2));
    }
    __syncthreads();

    // per-thread x constants (4 consecutive columns)
    const int xg   = (threadIdx.x & 127) << 2;  // 0..508
    const int rsub = threadIdx.x >> 7;          // 0 or 1 (wave-uniform)

    float cx1[4], sx1[4], cx2[4], sx2[4];
#pragma unroll
    for (int j = 0; j < 4; ++j) {
        const int xx = xg + j;
        sincosf(float((w0  * xx) & 511) * STEP, &sx1[j], &cx1[j]);
        sincosf(float((w0r * xx) & 511) * STEP, &sx2[j], &cx2[j]);
    }

    const size_t plane_off = (size_t)pl * (size_t)(H * W);
#pragma unroll 4
    for (int it = 0; it < ROWS; it += 2) {
        const int r = it + rsub;
        const int y = row0 + r;
        const float4 ab = rowtab[r];   // wave-uniform -> LDS broadcast
        const size_t off = plane_off + (size_t)y * W + (size_t)xg;
        const float4 vi = *reinterpret_cast<const float4*>(xin + off);
        float4 vo;
        const float* pi = &vi.x;
        float*       po = &vo.x;
#pragma unroll
        for (int j = 0; j < 4; ++j) {
            float v = cx1[j] * ab.x + sx1[j] * ab.y + cx2[j] * ab.z + sx2[j] * ab.w;
            po[j] = fminf(fmaxf(fmaf(g, v, pi[j]), 0.0f), 1.0f);
        }
        *reinterpret_cast<float4*>(out + off) = vo;
    }
}

} // namespace

extern "C" void kernel_launch(void* const* d_in, const int* in_sizes, int n_in,
                              void* d_out, int out_size, void* d_ws, size_t ws_size,
                              hipStream_t stream) {
    const float* x         = (const float*)d_in[0];
    const float* phases    = (const float*)d_in[1];
    const float* strengths = (const float*)d_in[2];
    const int*   idx_h     = (const int*)d_in[3];
    const int*   idx_w     = (const int*)d_in[4];
    float*       out       = (float*)d_out;

    dim3 grid(H / ROWS, B * C);  // 16 row-tiles x 96 planes = 1536 blocks
    fourier_noise_kernel<<<grid, dim3(TPB), 0, stream>>>(
        x, phases, strengths, idx_h, idx_w, out);
}

// Round 3
// 181.995 us; speedup vs baseline: 1.0763x; 1.0763x over previous
//
#include <hip/hip_runtime.h>
#include <math.h>

// Closed-form replacement for the reference:
//   - spectrum has exactly 2 nonzero bins per (b,c) plane: (h0,w0) and (511-h0,511-w0),
//     both with value 1 + i*phase
//   - ifft2 real part: v[y,x] = cos(t1) - p*sin(t1) + cos(t2) - p*sin(t2), scaled 1/(H*W)
//     t1 = 2*pi*((h0*y + w0*x) mod 512)/512 ; t2 with (511-h0, 511-w0)
//   - Parseval gives the plane L2 norm analytically: sum(w^2) = S/(H*W),
//     S = s1 + s2, s_i = (1+p^2)/2 unless the bin is self-conjugate (then 1)
//   - out = clip(x + 16*strength/(512*sqrt(S)) * v, 0, 1)
//
// R1 -> R2: latency-bound (VALUBusy 9.6%, Occ 40%, 2.1 TB/s). ROWS 32->8
// (1536 -> 6144 blocks, 3 residency rounds), hoisted loads (4-deep MLP),
// nontemporal stores (out is streaming; keep L3 for x).
// R2 -> R3: compile fix — __builtin_nontemporal_store needs a clang native
// vector type, not HIP_vector_type float4.

namespace {

constexpr int H = 512, W = 512, B = 32, C = 3;
constexpr int ROWS = 8;    // rows of one plane handled per block
constexpr int TPB = 256;   // 128 float4-lanes cover a 512-wide row; 2 rows at a time

typedef float floatx4 __attribute__((ext_vector_type(4)));

__global__ __launch_bounds__(TPB) void fourier_noise_kernel(
    const float* __restrict__ xin,
    const float* __restrict__ phases,
    const float* __restrict__ strengths,
    const int* __restrict__ idx_h,
    const int* __restrict__ idx_w,
    float* __restrict__ out)
{
    const int pl = blockIdx.y;            // plane 0..95  (= b*C + c)
    const int b  = pl / C;
    const int c  = pl % C;

    // invert the CRT pairing: find i in [0,96) with i%32==b, i%3==c
    // i = b + 32k, 32 == 2 (mod 3)  =>  2k == c-b (mod 3)  =>  k == 2*(c-b) (mod 3)
    int d = (c - b) % 3; if (d < 0) d += 3;
    const int k = (2 * d) % 3;
    const int i = b + B * k;

    const int   h0 = idx_h[i];
    const int   w0 = idx_w[i];
    const float p  = phases[i];
    const float st = strengths[b * C + c];

    // analytic plane norm (Parseval)
    const float halfE = 0.5f * (1.0f + p * p);
    const float s1 = (((h0 & 255) == 0) && ((w0 & 255) == 0)) ? 1.0f : halfE;
    const float s2 = ((h0 == 255 || h0 == 511) && (w0 == 255 || w0 == 511)) ? 1.0f : halfE;
    const float S  = s1 + s2;
    // g = scale * strength / sqrt(H*W*S),  scale = 512/32 = 16, sqrt(H*W)=512
    const float g = (16.0f / 512.0f) * st * rsqrtf(S);

    const int h0r = 511 - h0;
    const int w0r = 511 - w0;
    constexpr float STEP = 6.28318530717958647692f / 512.0f;  // 2*pi/512

    // per-row folded coefficients: v = cx1*A1 + sx1*B1 + cx2*A2 + sx2*B2
    __shared__ floatx4 rowtab[ROWS];
    const int row0 = blockIdx.x * ROWS;
    if (threadIdx.x < ROWS) {
        const int y = row0 + threadIdx.x;
        float sy1, cy1, sy2, cy2;
        sincosf(float((h0  * y) & 511) * STEP, &sy1, &cy1);
        sincosf(float((h0r * y) & 511) * STEP, &sy2, &cy2);
        floatx4 rt;
        rt.x = fmaf(-p, sy1, cy1);
        rt.y = -fmaf(p, cy1, sy1);
        rt.z = fmaf(-p, sy2, cy2);
        rt.w = -fmaf(p, cy2, sy2);
        rowtab[threadIdx.x] = rt;
    }

    // per-thread column geometry (4 consecutive columns)
    const int xg   = (threadIdx.x & 127) << 2;  // 0..508
    const int rsub = threadIdx.x >> 7;          // 0 or 1 (wave-uniform)
    const size_t plane_off = (size_t)pl * (size_t)(H * W);

    // issue all global loads up front — 4-deep MLP, independent of trig
    const size_t off0 = plane_off + (size_t)(row0 + 0 + rsub) * W + (size_t)xg;
    const size_t off1 = plane_off + (size_t)(row0 + 2 + rsub) * W + (size_t)xg;
    const size_t off2 = plane_off + (size_t)(row0 + 4 + rsub) * W + (size_t)xg;
    const size_t off3 = plane_off + (size_t)(row0 + 6 + rsub) * W + (size_t)xg;
    const floatx4 vi0 = *reinterpret_cast<const floatx4*>(xin + off0);
    const floatx4 vi1 = *reinterpret_cast<const floatx4*>(xin + off1);
    const floatx4 vi2 = *reinterpret_cast<const floatx4*>(xin + off2);
    const floatx4 vi3 = *reinterpret_cast<const floatx4*>(xin + off3);

    // per-thread column trig (overlaps with loads in flight)
    float cx1[4], sx1[4], cx2[4], sx2[4];
#pragma unroll
    for (int j = 0; j < 4; ++j) {
        const int xx = xg + j;
        sincosf(float((w0  * xx) & 511) * STEP, &sx1[j], &cx1[j]);
        sincosf(float((w0r * xx) & 511) * STEP, &sx2[j], &cx2[j]);
    }

    __syncthreads();

#define DO_ROW(vi, off, it)                                                     \
    {                                                                           \
        const floatx4 ab = rowtab[(it) * 2 + rsub]; /* wave-uniform broadcast */\
        floatx4 vo;                                                             \
        _Pragma("unroll")                                                       \
        for (int j = 0; j < 4; ++j) {                                           \
            float v = cx1[j] * ab.x + sx1[j] * ab.y                             \
                    + cx2[j] * ab.z + sx2[j] * ab.w;                            \
            vo[j] = fminf(fmaxf(fmaf(g, v, vi[j]), 0.0f), 1.0f);                \
        }                                                                       \
        __builtin_nontemporal_store(vo, reinterpret_cast<floatx4*>(out + off)); \
    }

    DO_ROW(vi0, off0, 0)
    DO_ROW(vi1, off1, 1)
    DO_ROW(vi2, off2, 2)
    DO_ROW(vi3, off3, 3)
#undef DO_ROW
}

} // namespace

extern "C" void kernel_launch(void* const* d_in, const int* in_sizes, int n_in,
                              void* d_out, int out_size, void* d_ws, size_t ws_size,
                              hipStream_t stream) {
    const float* x         = (const float*)d_in[0];
    const float* phases    = (const float*)d_in[1];
    const float* strengths = (const float*)d_in[2];
    const int*   idx_h     = (const int*)d_in[3];
    const int*   idx_w     = (const int*)d_in[4];
    float*       out       = (float*)d_out;

    dim3 grid(H / ROWS, B * C);  // 64 row-tiles x 96 planes = 6144 blocks
    fourier_noise_kernel<<<grid, dim3(TPB), 0, stream>>>(
        x, phases, strengths, idx_h, idx_w, out);
}

// Round 4
// 181.748 us; speedup vs baseline: 1.0777x; 1.0014x over previous
//
#include <hip/hip_runtime.h>
#include <math.h>

// Closed-form replacement for the reference:
//   - spectrum has exactly 2 nonzero bins per (b,c) plane: (h0,w0) and (511-h0,511-w0),
//     both with value 1 + i*phase
//   - ifft2 real part: v[y,x] = cos(t1) - p*sin(t1) + cos(t2) - p*sin(t2), scaled 1/(H*W)
//     t1 = 2*pi*((h0*y + w0*x) mod 512)/512 ; t2 with (511-h0, 511-w0)
//   - Parseval: plane norm sum(w^2) = S/(H*W), S = s1+s2,
//     s_i = (1+p^2)/2 unless self-conjugate bin (then 1)
//   - out = clip(x + 16*strength/(512*sqrt(S)) * v, 0, 1)
//
// R1 -> R3: ROWS 32->8 (6144 blocks), hoisted 4-deep load MLP, nontemporal
//           stores. Kernel 74.9us -> <59us (dropped out of rocprof top-5).
// R3 -> R4: all angles lie on the 2pi/512 grid -> hardware v_sin/v_cos in
//           REVOLUTIONS (n/512, exact) replaces libm sincosf (~6x less setup
//           VALU). Trig now cheap enough to compute row coeffs per-thread:
//           drop LDS rowtab + __syncthreads. 32-bit offsets.

namespace {

constexpr int H = 512, W = 512, B = 32, C = 3;
constexpr int ROWS = 8;    // rows of one plane handled per block
constexpr int TPB = 256;   // 128 float4-lanes cover a 512-wide row; 2 rows at a time

typedef float floatx4 __attribute__((ext_vector_type(4)));

__global__ __launch_bounds__(TPB) void fourier_noise_kernel(
    const float* __restrict__ xin,
    const float* __restrict__ phases,
    const float* __restrict__ strengths,
    const int* __restrict__ idx_h,
    const int* __restrict__ idx_w,
    float* __restrict__ out)
{
    const int pl   = blockIdx.y;            // plane 0..95  (= b*C + c)
    const int row0 = blockIdx.x * ROWS;
    const int xg   = (threadIdx.x & 127) << 2;  // column group 0..508
    const int rsub = threadIdx.x >> 7;          // 0 or 1 (wave-uniform)

    // ---- issue all global loads first (independent of the scalar params) ----
    const uint32_t off0 = (uint32_t)pl * (uint32_t)(H * W)
                        + (uint32_t)(row0 + rsub) * (uint32_t)W + (uint32_t)xg;
    const uint32_t off1 = off0 + 2u * W;
    const uint32_t off2 = off0 + 4u * W;
    const uint32_t off3 = off0 + 6u * W;
    const floatx4 vi0 = *reinterpret_cast<const floatx4*>(xin + off0);
    const floatx4 vi1 = *reinterpret_cast<const floatx4*>(xin + off1);
    const floatx4 vi2 = *reinterpret_cast<const floatx4*>(xin + off2);
    const floatx4 vi3 = *reinterpret_cast<const floatx4*>(xin + off3);

    // ---- scalar params (wave-uniform) ----
    const int b = pl / C;
    const int c = pl % C;
    // invert CRT pairing: i in [0,96) with i%32==b, i%3==c
    int d = (c - b) % 3; if (d < 0) d += 3;
    const int i = b + B * ((2 * d) % 3);

    const int   h0 = idx_h[i];
    const int   w0 = idx_w[i];
    const float p  = phases[i];
    const float st = strengths[pl];

    // analytic plane norm (Parseval)
    const float halfE = 0.5f * (1.0f + p * p);
    const float s1 = (((h0 & 255) == 0) && ((w0 & 255) == 0)) ? 1.0f : halfE;
    const float s2 = ((h0 == 255 || h0 == 511) && (w0 == 255 || w0 == 511)) ? 1.0f : halfE;
    const float g  = (16.0f / 512.0f) * st * rsqrtf(s1 + s2);

    const int h0r = 511 - h0;
    const int w0r = 511 - w0;
    constexpr float INV = 1.0f / 512.0f;   // grid-index -> revolutions

    // ---- per-thread column trig: hw sin/cos on exact revolutions ----
    float cx1[4], sx1[4], cx2[4], sx2[4];
#pragma unroll
    for (int j = 0; j < 4; ++j) {
        const int xx = xg + j;
        const float a1 = (float)((w0  * xx) & 511) * INV;
        const float a2 = (float)((w0r * xx) & 511) * INV;
        sx1[j] = __builtin_amdgcn_sinf(a1);
        cx1[j] = __builtin_amdgcn_cosf(a1);
        sx2[j] = __builtin_amdgcn_sinf(a2);
        cx2[j] = __builtin_amdgcn_cosf(a2);
    }

    // ---- per-thread row coefficients (rows rsub, rsub+2, rsub+4, rsub+6) ----
    float A1[4], B1[4], A2[4], B2[4];
#pragma unroll
    for (int it = 0; it < 4; ++it) {
        const int y = row0 + rsub + 2 * it;
        const float a1 = (float)((h0  * y) & 511) * INV;
        const float a2 = (float)((h0r * y) & 511) * INV;
        const float sy1 = __builtin_amdgcn_sinf(a1);
        const float cy1 = __builtin_amdgcn_cosf(a1);
        const float sy2 = __builtin_amdgcn_sinf(a2);
        const float cy2 = __builtin_amdgcn_cosf(a2);
        A1[it] = fmaf(-p, sy1, cy1);  B1[it] = -fmaf(p, cy1, sy1);
        A2[it] = fmaf(-p, sy2, cy2);  B2[it] = -fmaf(p, cy2, sy2);
    }

#define DO_ROW(vi, off, it)                                                     \
    {                                                                           \
        floatx4 vo;                                                             \
        _Pragma("unroll")                                                       \
        for (int j = 0; j < 4; ++j) {                                           \
            float v = cx1[j] * A1[it] + sx1[j] * B1[it]                         \
                    + cx2[j] * A2[it] + sx2[j] * B2[it];                        \
            vo[j] = fminf(fmaxf(fmaf(g, v, vi[j]), 0.0f), 1.0f);                \
        }                                                                       \
        __builtin_nontemporal_store(vo, reinterpret_cast<floatx4*>(out + off)); \
    }

    DO_ROW(vi0, off0, 0)
    DO_ROW(vi1, off1, 1)
    DO_ROW(vi2, off2, 2)
    DO_ROW(vi3, off3, 3)
#undef DO_ROW
}

} // namespace

extern "C" void kernel_launch(void* const* d_in, const int* in_sizes, int n_in,
                              void* d_out, int out_size, void* d_ws, size_t ws_size,
                              hipStream_t stream) {
    const float* x         = (const float*)d_in[0];
    const float* phases    = (const float*)d_in[1];
    const float* strengths = (const float*)d_in[2];
    const int*   idx_h     = (const int*)d_in[3];
    const int*   idx_w     = (const int*)d_in[4];
    float*       out       = (float*)d_out;

    dim3 grid(H / ROWS, B * C);  // 64 row-tiles x 96 planes = 6144 blocks
    fourier_noise_kernel<<<grid, dim3(TPB), 0, stream>>>(
        x, phases, strengths, idx_h, idx_w, out);
}